// Round 12
// baseline (210.267 us; speedup 1.0000x reference)
//
#include <hip/hip_runtime.h>
#include <hip/hip_fp16.h>
#include <math.h>

#define N_NODES 50000
#define N_EDGES 800000
#define BIGV 1000000000.0f
#define NBLK_GEMM 3125  // 50000 / 16 nodes per block
#define CHUNK 1024      // edges per chunk (pass A granularity)
#define NCHUNK 782      // ceil(800000/1024)
#define NCH4 784        // chunk count padded to multiple of 4
#define NBUCKET 1563    // dst>>5 in [0,1562]  (32 nodes per bucket)
#define NBK4 1564       // bucket count padded to multiple of 4
#define BMAX 768        // LDS record capacity per bucket (Poisson(512)+11sigma)
#define OVFSTRIDE 1024  // global spill slots per bucket
#define NBLK_BN 512     // bnstats partial blocks

typedef _Float16 half8 __attribute__((ext_vector_type(8)));
typedef float floatx4 __attribute__((ext_vector_type(4)));

__device__ __forceinline__ float clampinf(float x) { return isinf(x) ? BIGV : x; }

// monotone float->int key for LDS atomicMax-based segment max (exact semantics)
__device__ __forceinline__ int fkey(float x) {
    int b = __float_as_int(x);
    return (b >= 0) ? b : (b ^ 0x7FFFFFFF);
}
__device__ __forceinline__ float fkey_inv(int k) {
    return __int_as_float((k >= 0) ? k : (k ^ 0x7FFFFFFF));
}

// lgkm-only workgroup barrier: leaves global stores in flight.
__device__ __forceinline__ void barrier_lgkm_only() {
    __builtin_amdgcn_sched_barrier(0);
    asm volatile("s_waitcnt lgkmcnt(0)" ::: "memory");
    __builtin_amdgcn_s_barrier();
    __builtin_amdgcn_sched_barrier(0);
}

// ---------------------------------------------------------------------------
// k_prep: W pre-cast (fp16 W^T) + bns zero + per-chunk bucket histogram.
// Buckets: dst>>5 (1563 x ~512 edges). countsT[bucket][chunk].
// ---------------------------------------------------------------------------
__global__ __launch_bounds__(256) void k_prep(const float* __restrict__ W,
                                              __half* __restrict__ wt,
                                              float* __restrict__ bns,
                                              const int* __restrict__ dst,
                                              int* __restrict__ countsT)
{
    __shared__ int hist[NBK4];
    const int t = threadIdx.x;
    const int idx = blockIdx.x * 256 + t;
    if (idx < 16384) {
        int n = idx >> 7, k = idx & 127;
        wt[idx] = __float2half(W[k * 128 + n]);
    }
    if (idx < 256) bns[idx] = 0.f;
    for (int i = t; i < NBK4; i += 256) hist[i] = 0;
    __syncthreads();
    const int base = blockIdx.x * CHUNK;
    for (int i = t; i < CHUNK; i += 256) {
        int e = base + i;
        if (e < N_EDGES) atomicAdd(&hist[dst[e] >> 5], 1);   // LDS atomic
    }
    __syncthreads();
    for (int i = t; i < NBK4; i += 256)
        countsT[(size_t)i * NCH4 + blockIdx.x] = hist[i];    // [bucket][chunk]
}

// ---------------------------------------------------------------------------
// k_off: one wave per bucket — exclusive prefix over the 782 chunks via
// 13-pass shfl_up wave-scan; writes cursC[chunk][bucket] + btot[bucket].
// ---------------------------------------------------------------------------
__global__ __launch_bounds__(256) void k_off(const int* __restrict__ countsT,
                                             int* __restrict__ cursC,
                                             int* __restrict__ btot)
{
    const int wv = (blockIdx.x << 2) + (threadIdx.x >> 6);   // bucket id
    const int l = threadIdx.x & 63;
    if (wv >= NBUCKET) {
        if (l == 0 && wv < NBK4) btot[wv] = 0;
        return;
    }
    const int* row = countsT + (size_t)wv * NCH4;
    int carry = 0;
    #pragma unroll
    for (int p = 0; p < 13; ++p) {                           // 13*64 = 832 >= 782
        const int c = p * 64 + l;
        const int v = (c < NCHUNK) ? row[c] : 0;
        int x = v;
        #pragma unroll
        for (int o = 1; o < 64; o <<= 1) {
            int u = __shfl_up(x, o);
            if (l >= o) x += u;
        }
        if (c < NCHUNK) cursC[(size_t)c * NBK4 + wv] = carry + x - v;
        carry += __shfl(x, 63);
    }
    if (l == 0) btot[wv] = carry;
}

// ---------------------------------------------------------------------------
// K1: z = h @ W + b via MFMA f16, fp16 z out, fused per-node scores.
// ---------------------------------------------------------------------------
__global__ __launch_bounds__(256) void k_gemm(
    const float* __restrict__ h, const __half* __restrict__ wt,
    const float* __restrict__ bias, const float* __restrict__ attn_w,
    __half* __restrict__ zh, float* __restrict__ sv, float* __restrict__ tv)
{
    __shared__ _Float16 hA[16][136];
    __shared__ float spart[4][16], tpart[4][16];

    const int tid = threadIdx.x;
    const int lane = tid & 63;
    const int wv = tid >> 6;          // wave 0..3
    const int l16 = lane & 15;
    const int oct = lane >> 4;
    const int n0 = wv << 5;           // this wave's 32-col strip
    const int node0 = blockIdx.x << 4;

    // stage h tile as fp16 (512 float4; 32 float4 per row)
    {
        const float4* h4 = (const float4*)(h + (size_t)node0 * 128);
        for (int i = tid; i < 512; i += 256) {
            int r = i >> 5, c4 = i & 31;
            float4 v = h4[i];
            union { __half2 h2[2]; uint2 u; } pk;
            pk.h2[0] = __floats2half2_rn(v.x, v.y);
            pk.h2[1] = __floats2half2_rn(v.z, v.w);
            *(uint2*)&hA[r][c4 << 2] = pk.u;
        }
    }

    // B-fragments in registers
    half8 bfrag[4][2];
    #pragma unroll
    for (int kk = 0; kk < 4; ++kk)
        #pragma unroll
        for (int t = 0; t < 2; ++t)
            bfrag[kk][t] = *(const half8*)(wt + (size_t)(n0 + t * 16 + l16) * 128
                                              + kk * 32 + oct * 8);

    const float bv0 = bias[n0 + l16],         bv1 = bias[n0 + 16 + l16];
    const float ws0 = attn_w[n0 + l16],       ws1 = attn_w[n0 + 16 + l16];
    const float wd0 = attn_w[128 + n0 + l16], wd1 = attn_w[128 + n0 + 16 + l16];

    barrier_lgkm_only();   // staging visible; global loads stay in flight

    floatx4 acc0 = {0.f, 0.f, 0.f, 0.f};
    floatx4 acc1 = {0.f, 0.f, 0.f, 0.f};
    #pragma unroll
    for (int kk = 0; kk < 4; ++kk) {
        half8 a = *(const half8*)&hA[l16][(kk << 5) + (oct << 3)];
        acc0 = __builtin_amdgcn_mfma_f32_16x16x32_f16(a, bfrag[kk][0], acc0, 0, 0, 0);
        acc1 = __builtin_amdgcn_mfma_f32_16x16x32_f16(a, bfrag[kk][1], acc1, 0, 0, 0);
    }

    float s_acc[4], t_acc[4];
    #pragma unroll
    for (int r = 0; r < 4; ++r) {
        float z0 = clampinf(acc0[r] + bv0);
        float z1 = clampinf(acc1[r] + bv1);
        const int row = (oct << 2) + r;
        zh[(size_t)(node0 + row) * 128 + n0 + l16]      = __float2half(z0);
        zh[(size_t)(node0 + row) * 128 + n0 + 16 + l16] = __float2half(z1);
        s_acc[r] = z0 * ws0 + z1 * ws1;
        t_acc[r] = z0 * wd0 + z1 * wd1;
    }
    #pragma unroll
    for (int r = 0; r < 4; ++r) {
        #pragma unroll
        for (int o = 1; o < 16; o <<= 1) {
            s_acc[r] += __shfl_xor(s_acc[r], o);
            t_acc[r] += __shfl_xor(t_acc[r], o);
        }
    }
    if (l16 == 0) {
        #pragma unroll
        for (int r = 0; r < 4; ++r) {
            spart[wv][(oct << 2) + r] = s_acc[r];
            tpart[wv][(oct << 2) + r] = t_acc[r];
        }
    }
    barrier_lgkm_only();
    if (tid < 16) {
        sv[node0 + tid] = spart[0][tid] + spart[1][tid] + spart[2][tid] + spart[3][tid];
        tv[node0 + tid] = tpart[0][tid] + tpart[1][tid] + tpart[2][tid] + tpart[3][tid];
    }
}

// ---------------------------------------------------------------------------
// PASS A (k_scat): per 1024-edge chunk, 512 threads. Coalesced cursC row +
// redundant btot scan for bucket bases, then scatter final 16B records into
// bucket slices via LDS cursors. Block 0 publishes bbase.
// ---------------------------------------------------------------------------
__global__ __launch_bounds__(512) void k_scat(
    const int* __restrict__ src, const int* __restrict__ dst,
    const float* __restrict__ sigma,
    const float* __restrict__ sv, const float* __restrict__ tv,
    const float* __restrict__ attn_b,
    const int* __restrict__ cursC, const int* __restrict__ btot,
    float4* __restrict__ tmp, int* __restrict__ bbase_g)
{
    __shared__ int cur[NBK4];
    __shared__ int bb[NBK4];
    __shared__ int tsc[512];
    const int t = threadIdx.x;
    const int self = blockIdx.x;

    for (int i = t; i < NBK4; i += 512) cur[i] = cursC[(size_t)self * NBK4 + i];

    uint4 bt = {0u, 0u, 0u, 0u};
    int tsum = 0;
    if (t < NBK4 / 4) {                          // 391 quads
        bt = ((const uint4*)btot)[t];
        tsum = (int)(bt.x + bt.y + bt.z + bt.w);
    }
    tsc[t] = tsum;
    __syncthreads();
    for (int off = 1; off < 512; off <<= 1) {    // inclusive block scan
        int u = (t >= off) ? tsc[t - off] : 0;
        __syncthreads();
        tsc[t] += u;
        __syncthreads();
    }
    if (t < NBK4 / 4) {
        const int v0 = tsc[t] - tsum;            // exclusive
        bb[4*t+0] = v0;
        bb[4*t+1] = v0 + (int)bt.x;
        bb[4*t+2] = v0 + (int)bt.x + (int)bt.y;
        bb[4*t+3] = v0 + (int)bt.x + (int)bt.y + (int)bt.z;
    }
    __syncthreads();
    for (int i = t; i < NBK4; i += 512) cur[i] += bb[i];
    if (self == 0)
        for (int i = t; i < NBK4; i += 512) bbase_g[i] = bb[i];
    __syncthreads();

    const float ab = attn_b[0];
    const int base = self * CHUNK;
    for (int i = t; i < CHUNK; i += 512) {
        int e = base + i;
        if (e < N_EDGES) {
            int s = src[e];
            int d = dst[e];
            float a = sv[s] + tv[d] + ab;
            a = clampinf(a);
            float ev = a > 0.f ? a : 0.01f * a;  // leaky relu
            int pos = atomicAdd(&cur[d >> 5], 1);  // LDS atomic
            float4 rec;
            rec.x = __int_as_float(s);
            rec.y = sigma[e];
            rec.z = ev;
            rec.w = __int_as_float(d);
            tmp[pos] = rec;
        }
    }
}

// ---------------------------------------------------------------------------
// k_bagg: fused bin + edge-parallel softmax + gather-aggregate.
// R11 post-mortem: edge-parallel softmax worked (51.5->43.2us) but both
// pipes remain half-idle (VALU 35%, HBM 31%) — per-node gather still has
// only 4 loads in flight (deg~16 = one loop iteration), then a dependent
// tail before the next node's loads issue. THIS ROUND: 2-node INTERLEAVED
// gather — each wave processes its 4 nodes as two pairs (jA, jB=jA+16) with
// dual accumulators; both nodes' loads issue back-to-back = 8 loads in
// flight per wave (2x MLP). Fallback paths (n>BMAX) keep old structure.
// ---------------------------------------------------------------------------
__global__ __launch_bounds__(512) void k_bagg(
    const float4* __restrict__ tmp, const int* __restrict__ bbase_g,
    const __half* __restrict__ zh, float4* __restrict__ ovf,
    float* __restrict__ out)
{
    __shared__ float4 lrec[BMAX];
    __shared__ int hist[32];
    __shared__ int segs[33];
    __shared__ int cur[32];
    __shared__ int mkey[32];
    __shared__ float dnod[32], bsum[32], scale[32];
    const int t = threadIdx.x;
    const int b = blockIdx.x;
    const int s0 = bbase_g[b];
    const int n  = bbase_g[b + 1] - s0;          // bbase_g[1563] == N_EDGES

    if (t < 32) {
        hist[t] = 0; mkey[t] = (int)0x80000000;
        dnod[t] = 0.f; bsum[t] = 0.f;
    }
    __syncthreads();

    // phase 1: histogram; hold up to 2 records in registers
    float4 rec0, rec1;
    const bool h0 = (t < n), h1 = (t + 512 < n);
    if (h0) rec0 = tmp[s0 + t];
    if (h1) rec1 = tmp[s0 + t + 512];
    if (h0) atomicAdd(&hist[__float_as_int(rec0.w) & 31], 1);
    if (h1) atomicAdd(&hist[__float_as_int(rec1.w) & 31], 1);
    for (int i = t + 1024; i < n; i += 512)
        atomicAdd(&hist[__float_as_int(tmp[s0 + i].w) & 31], 1);
    __syncthreads();
    // 32-bin exclusive scan (lanes 0..31 of wave 0)
    if (t < 32) {
        const int hv = hist[t];
        int x = hv;
        #pragma unroll
        for (int o = 1; o < 32; o <<= 1) {
            int u = __shfl_up(x, o);
            if (t >= o) x += u;
        }
        segs[t] = x - hv;
        cur[t]  = x - hv;
        if (t == 31) segs[32] = x;
    }
    __syncthreads();
    // phase 2: place records + accumulate bsum + segment max (LDS atomics)
    if (h0) {
        const int bin = __float_as_int(rec0.w) & 31;
        int pos = atomicAdd(&cur[bin], 1);
        if (pos < BMAX) lrec[pos] = rec0;
        else            ovf[(size_t)b * OVFSTRIDE + (pos - BMAX)] = rec0;
        atomicAdd(&bsum[bin], rec0.y);
        atomicMax(&mkey[bin], fkey(rec0.z));
    }
    if (h1) {
        const int bin = __float_as_int(rec1.w) & 31;
        int pos = atomicAdd(&cur[bin], 1);
        if (pos < BMAX) lrec[pos] = rec1;
        else            ovf[(size_t)b * OVFSTRIDE + (pos - BMAX)] = rec1;
        atomicAdd(&bsum[bin], rec1.y);
        atomicMax(&mkey[bin], fkey(rec1.z));
    }
    for (int i = t + 1024; i < n; i += 512) {
        float4 rec = tmp[s0 + i];
        const int bin = __float_as_int(rec.w) & 31;
        int pos = atomicAdd(&cur[bin], 1);
        if (pos < BMAX) lrec[pos] = rec;
        else            ovf[(size_t)b * OVFSTRIDE + (pos - BMAX)] = rec;
        atomicAdd(&bsum[bin], rec.y);
        atomicMax(&mkey[bin], fkey(rec.z));
    }
    __syncthreads();
    // phase 2b (edge-parallel softmax): p = exp(e - m); dn += p; .w = p*sigma
    if (n <= BMAX) {
        for (int i = t; i < n; i += 512) {
            float4 r = lrec[i];
            const int bin = __float_as_int(r.w) & 31;
            const float m = fkey_inv(mkey[bin]);
            const float p = __expf(r.z - m);
            atomicAdd(&dnod[bin], p);
            lrec[i].w = p * r.y;
        }
    }
    __syncthreads();
    if (t < 32) scale[t] = (1.0f / dnod[t]) / (bsum[t] + 1e-6f);
    __syncthreads();

    // phase 3: pure gather
    const int lane = t & 63;
    const int wv = t >> 6;
    const int grp = lane >> 4;
    const int l16 = lane & 15;

    if (n <= BMAX) {
        // ---- fast path: 2-node interleaved, shfl-free, 8 loads in flight ----
        #pragma unroll
        for (int jp = 0; jp < 2; ++jp) {
            const int jA = wv + (jp << 3);       // wv, wv+8
            const int jB = jA + 16;              // wv+16, wv+24
            const int nodeA = (b << 5) + jA;
            const int nodeB = (b << 5) + jB;
            const int begA = segs[jA], degA = segs[jA + 1] - begA;
            const int begB = segs[jB], degB = segs[jB + 1] - begB;
            const float scA = scale[jA], scB = scale[jB];
            const int dmA = (degA > 0) ? degA - 1 : 0;
            const int dmB = (degB > 0) ? degB - 1 : 0;
            float accA[8] = {0.f,0.f,0.f,0.f,0.f,0.f,0.f,0.f};
            float accB[8] = {0.f,0.f,0.f,0.f,0.f,0.f,0.f,0.f};
            const int cmax = max(degA, degB);

            for (int c = 0; c < cmax; c += 16) {
                const int j0 = c + grp, j1 = j0 + 4, j2 = j0 + 8, j3 = j0 + 12;
                // LDS broadcasts (clamped indices stay within lrec/LDS block)
                float4 qA0 = lrec[begA + min(j0, dmA)];
                float4 qA1 = lrec[begA + min(j1, dmA)];
                float4 qA2 = lrec[begA + min(j2, dmA)];
                float4 qA3 = lrec[begA + min(j3, dmA)];
                float4 qB0 = lrec[begB + min(j0, dmB)];
                float4 qB1 = lrec[begB + min(j1, dmB)];
                float4 qB2 = lrec[begB + min(j2, dmB)];
                float4 qB3 = lrec[begB + min(j3, dmB)];
                // 8 independent global loads in flight
                uint4 rA0 = *(const uint4*)(zh + ((size_t)__float_as_int(qA0.x) << 7) + (l16 << 3));
                uint4 rA1 = *(const uint4*)(zh + ((size_t)__float_as_int(qA1.x) << 7) + (l16 << 3));
                uint4 rA2 = *(const uint4*)(zh + ((size_t)__float_as_int(qA2.x) << 7) + (l16 << 3));
                uint4 rA3 = *(const uint4*)(zh + ((size_t)__float_as_int(qA3.x) << 7) + (l16 << 3));
                uint4 rB0 = *(const uint4*)(zh + ((size_t)__float_as_int(qB0.x) << 7) + (l16 << 3));
                uint4 rB1 = *(const uint4*)(zh + ((size_t)__float_as_int(qB1.x) << 7) + (l16 << 3));
                uint4 rB2 = *(const uint4*)(zh + ((size_t)__float_as_int(qB2.x) << 7) + (l16 << 3));
                uint4 rB3 = *(const uint4*)(zh + ((size_t)__float_as_int(qB3.x) << 7) + (l16 << 3));
                const float cA0 = (j0 < degA) ? qA0.w * scA : 0.f;
                const float cA1 = (j1 < degA) ? qA1.w * scA : 0.f;
                const float cA2 = (j2 < degA) ? qA2.w * scA : 0.f;
                const float cA3 = (j3 < degA) ? qA3.w * scA : 0.f;
                const float cB0 = (j0 < degB) ? qB0.w * scB : 0.f;
                const float cB1 = (j1 < degB) ? qB1.w * scB : 0.f;
                const float cB2 = (j2 < degB) ? qB2.w * scB : 0.f;
                const float cB3 = (j3 < degB) ? qB3.w * scB : 0.f;
                const __half2* hA0 = (const __half2*)&rA0;
                const __half2* hA1 = (const __half2*)&rA1;
                const __half2* hA2 = (const __half2*)&rA2;
                const __half2* hA3 = (const __half2*)&rA3;
                const __half2* hB0 = (const __half2*)&rB0;
                const __half2* hB1 = (const __half2*)&rB1;
                const __half2* hB2 = (const __half2*)&rB2;
                const __half2* hB3 = (const __half2*)&rB3;
                #pragma unroll
                for (int k = 0; k < 4; ++k) {
                    float2 fA0 = __half22float2(hA0[k]);
                    float2 fA1 = __half22float2(hA1[k]);
                    float2 fA2 = __half22float2(hA2[k]);
                    float2 fA3 = __half22float2(hA3[k]);
                    accA[2*k]   = fmaf(cA0, fA0.x, accA[2*k]);
                    accA[2*k+1] = fmaf(cA0, fA0.y, accA[2*k+1]);
                    accA[2*k]   = fmaf(cA1, fA1.x, accA[2*k]);
                    accA[2*k+1] = fmaf(cA1, fA1.y, accA[2*k+1]);
                    accA[2*k]   = fmaf(cA2, fA2.x, accA[2*k]);
                    accA[2*k+1] = fmaf(cA2, fA2.y, accA[2*k+1]);
                    accA[2*k]   = fmaf(cA3, fA3.x, accA[2*k]);
                    accA[2*k+1] = fmaf(cA3, fA3.y, accA[2*k+1]);
                    float2 fB0 = __half22float2(hB0[k]);
                    float2 fB1 = __half22float2(hB1[k]);
                    float2 fB2 = __half22float2(hB2[k]);
                    float2 fB3 = __half22float2(hB3[k]);
                    accB[2*k]   = fmaf(cB0, fB0.x, accB[2*k]);
                    accB[2*k+1] = fmaf(cB0, fB0.y, accB[2*k+1]);
                    accB[2*k]   = fmaf(cB1, fB1.x, accB[2*k]);
                    accB[2*k+1] = fmaf(cB1, fB1.y, accB[2*k+1]);
                    accB[2*k]   = fmaf(cB2, fB2.x, accB[2*k]);
                    accB[2*k+1] = fmaf(cB2, fB2.y, accB[2*k+1]);
                    accB[2*k]   = fmaf(cB3, fB3.x, accB[2*k]);
                    accB[2*k+1] = fmaf(cB3, fB3.y, accB[2*k+1]);
                }
            }
            // combine 4 groups + write both nodes
            #pragma unroll
            for (int k = 0; k < 8; ++k) {
                accA[k] += __shfl_xor(accA[k], 16);
                accA[k] += __shfl_xor(accA[k], 32);
                accB[k] += __shfl_xor(accB[k], 16);
                accB[k] += __shfl_xor(accB[k], 32);
            }
            if (grp == 0) {
                if (nodeA < N_NODES) {
                    float4 o0, o1;
                    o0.x = clampinf(accA[0]); o0.y = clampinf(accA[1]);
                    o0.z = clampinf(accA[2]); o0.w = clampinf(accA[3]);
                    o1.x = clampinf(accA[4]); o1.y = clampinf(accA[5]);
                    o1.z = clampinf(accA[6]); o1.w = clampinf(accA[7]);
                    float4* op = (float4*)(out + (size_t)nodeA * 128 + (l16 << 3));
                    op[0] = o0; op[1] = o1;
                }
                if (nodeB < N_NODES) {
                    float4 o0, o1;
                    o0.x = clampinf(accB[0]); o0.y = clampinf(accB[1]);
                    o0.z = clampinf(accB[2]); o0.w = clampinf(accB[3]);
                    o1.x = clampinf(accB[4]); o1.y = clampinf(accB[5]);
                    o1.z = clampinf(accB[6]); o1.w = clampinf(accB[7]);
                    float4* op = (float4*)(out + (size_t)nodeB * 128 + (l16 << 3));
                    op[0] = o0; op[1] = o1;
                }
            }
        }
    } else {
        // ---- spill fallback (n > BMAX; ~impossible): per-node, old paths.
        //      .y (sigma) / .z (e) intact since phase 2b was skipped.
        for (int j = wv; j < 32; j += 8) {
            const int node = (b << 5) + j;
            if (node >= N_NODES) continue;
            const int beg = segs[j];
            const int deg = segs[j + 1] - beg;
            float acc[8] = {0.f,0.f,0.f,0.f,0.f,0.f,0.f,0.f};

            if (deg > 0) {
                if (deg <= 64) {
                    int sidx = 0; float sig = 0.f, e = -INFINITY;
                    if (lane < deg) {
                        const int off = beg + lane;
                        float4 r = (off < BMAX) ? lrec[off]
                                 : ovf[(size_t)b * OVFSTRIDE + (off - BMAX)];
                        sidx = __float_as_int(r.x); sig = r.y; e = r.z;
                    }
                    float m = e;
                    for (int o = 32; o; o >>= 1) m = fmaxf(m, __shfl_xor(m, o));
                    float p = (lane < deg) ? __expf(e - m) : 0.f;
                    float dn = p, bs = sig;
                    for (int o = 32; o; o >>= 1) {
                        dn += __shfl_xor(dn, o);
                        bs += __shfl_xor(bs, o);
                    }
                    const float coef = p * sig * (1.0f / dn) / (bs + 1e-6f);
                    for (int c = 0; c < deg; c += 4) {
                        const int jj = c + grp;
                        const int js = (jj < deg) ? jj : 0;
                        float cf = __shfl(coef, js);
                        int sj = __shfl(sidx, js);
                        if (jj < deg) {
                            uint4 raw = *(const uint4*)(zh + ((size_t)sj << 7) + (l16 << 3));
                            const __half2* hp = (const __half2*)&raw;
                            #pragma unroll
                            for (int k = 0; k < 4; ++k) {
                                float2 f = __half22float2(hp[k]);
                                acc[2*k]   = fmaf(cf, f.x, acc[2*k]);
                                acc[2*k+1] = fmaf(cf, f.y, acc[2*k+1]);
                            }
                        }
                    }
                } else {
                    float m = -INFINITY;
                    for (int i = lane; i < deg; i += 64) {
                        const int off = beg + i;
                        float4 r = (off < BMAX) ? lrec[off]
                                 : ovf[(size_t)b * OVFSTRIDE + (off - BMAX)];
                        m = fmaxf(m, r.z);
                    }
                    for (int o = 32; o; o >>= 1) m = fmaxf(m, __shfl_xor(m, o));
                    float dn = 0.f, bs = 0.f;
                    for (int i = lane; i < deg; i += 64) {
                        const int off = beg + i;
                        float4 r = (off < BMAX) ? lrec[off]
                                 : ovf[(size_t)b * OVFSTRIDE + (off - BMAX)];
                        dn += __expf(r.z - m); bs += r.y;
                    }
                    for (int o = 32; o; o >>= 1) {
                        dn += __shfl_xor(dn, o);
                        bs += __shfl_xor(bs, o);
                    }
                    const float scl = (1.0f / dn) / (bs + 1e-6f);
                    for (int c = 0; c < deg; c += 64) {
                        int i = c + lane;
                        int sidx = 0; float coef = 0.f;
                        if (i < deg) {
                            const int off = beg + i;
                            float4 r = (off < BMAX) ? lrec[off]
                                     : ovf[(size_t)b * OVFSTRIDE + (off - BMAX)];
                            sidx = __float_as_int(r.x);
                            coef = __expf(r.z - m) * r.y * scl;
                        }
                        const int cnt2 = min(64, deg - c);
                        for (int jj = 0; jj < cnt2; jj += 4) {
                            const int j4 = jj + grp;
                            const int js = (j4 < cnt2) ? j4 : 0;
                            float cf = __shfl(coef, js);
                            int sj = __shfl(sidx, js);
                            if (j4 < cnt2) {
                                uint4 raw = *(const uint4*)(zh + ((size_t)sj << 7) + (l16 << 3));
                                const __half2* hp = (const __half2*)&raw;
                                #pragma unroll
                                for (int k = 0; k < 4; ++k) {
                                    float2 f = __half22float2(hp[k]);
                                    acc[2*k]   = fmaf(cf, f.x, acc[2*k]);
                                    acc[2*k+1] = fmaf(cf, f.y, acc[2*k+1]);
                                }
                            }
                        }
                    }
                }
            }
            #pragma unroll
            for (int k = 0; k < 8; ++k) {
                acc[k] += __shfl_xor(acc[k], 16);
                acc[k] += __shfl_xor(acc[k], 32);
            }
            if (grp == 0) {
                float4 o0, o1;
                o0.x = clampinf(acc[0]); o0.y = clampinf(acc[1]);
                o0.z = clampinf(acc[2]); o0.w = clampinf(acc[3]);
                o1.x = clampinf(acc[4]); o1.y = clampinf(acc[5]);
                o1.z = clampinf(acc[6]); o1.w = clampinf(acc[7]);
                float4* op = (float4*)(out + (size_t)node * 128 + (l16 << 3));
                op[0] = o0; op[1] = o1;
            }
        }
    }
}

// ---------------------------------------------------------------------------
// BN stats (R7-proven): per-block non-atomic partials + 1-block reducer.
// ---------------------------------------------------------------------------
__global__ __launch_bounds__(256) void k_bnstats(const float* __restrict__ hnew,
                                                 float* __restrict__ partials)
{
    const int tid = threadIdx.x;
    const int f4 = (tid & 31) << 2;
    const int rgrp = tid >> 5;           // 0..7
    float4 s = {0.f, 0.f, 0.f, 0.f}, q = {0.f, 0.f, 0.f, 0.f};
    for (int node = blockIdx.x * 8 + rgrp; node < N_NODES; node += NBLK_BN * 8) {
        float4 v = *(const float4*)(hnew + (size_t)node * 128 + f4);
        s.x += v.x; s.y += v.y; s.z += v.z; s.w += v.w;
        q.x += v.x * v.x; q.y += v.y * v.y; q.z += v.z * v.z; q.w += v.w * v.w;
    }
    __shared__ float4 ls[256], lq[256];
    ls[tid] = s; lq[tid] = q;
    __syncthreads();
    for (int off = 128; off >= 32; off >>= 1) {
        if (tid < off) {
            float4 a = ls[tid + off], b = lq[tid + off];
            ls[tid].x += a.x; ls[tid].y += a.y; ls[tid].z += a.z; ls[tid].w += a.w;
            lq[tid].x += b.x; lq[tid].y += b.y; lq[tid].z += b.z; lq[tid].w += b.w;
        }
        __syncthreads();
    }
    if (tid < 32) {
        float* p = partials + (size_t)blockIdx.x * 256;
        *(float4*)(p + f4)       = ls[tid];
        *(float4*)(p + 128 + f4) = lq[tid];
    }
}

__global__ __launch_bounds__(1024) void k_bnred(const float* __restrict__ partials,
                                                float* __restrict__ sums)
{
    __shared__ float red[4][256];
    const int t = threadIdx.x;
    const int f = t & 255;
    const int part = t >> 8;             // 0..3, each covers 128 blocks
    float s = 0.f;
    #pragma unroll 8
    for (int b = part * (NBLK_BN / 4); b < (part + 1) * (NBLK_BN / 4); ++b)
        s += partials[(size_t)b * 256 + f];
    red[part][f] = s;
    __syncthreads();
    if (part == 0)
        sums[f] = red[0][f] + red[1][f] + red[2][f] + red[3][f];
}

// ---------------------------------------------------------------------------
// BN apply + ELU: float4-vectorized; per-feature scale/shift in LDS.
// ---------------------------------------------------------------------------
__global__ __launch_bounds__(256) void k_bnapply(float* __restrict__ io,
                                                 const float* __restrict__ sums,
                                                 const float* __restrict__ gamma,
                                                 const float* __restrict__ beta)
{
    __shared__ float sc[128], sh[128];
    const int tid = threadIdx.x;
    if (tid < 128) {
        const float invn = 1.0f / (float)N_NODES;
        float mu = sums[tid] * invn;
        float var = fmaxf(sums[128 + tid] * invn - mu * mu, 0.f);
        float g = gamma[tid] * rsqrtf(var + 1e-5f);
        sc[tid] = g;
        sh[tid] = beta[tid] - mu * g;
    }
    __syncthreads();
    const size_t idx = (size_t)blockIdx.x * 256 + tid;   // float4 index
    const int f4 = ((int)idx & 31) << 2;
    float4 x = ((const float4*)io)[idx];
    float y0 = x.x * sc[f4 + 0] + sh[f4 + 0];
    float y1 = x.y * sc[f4 + 1] + sh[f4 + 1];
    float y2 = x.z * sc[f4 + 2] + sh[f4 + 2];
    float y3 = x.w * sc[f4 + 3] + sh[f4 + 3];
    float4 o;
    o.x = y0 > 0.f ? y0 : expm1f(y0);
    o.y = y1 > 0.f ? y1 : expm1f(y1);
    o.z = y2 > 0.f ? y2 : expm1f(y2);
    o.w = y3 > 0.f ? y3 : expm1f(y3);
    ((float4*)io)[idx] = o;
}

// ---------------------------------------------------------------------------
extern "C" void kernel_launch(void* const* d_in, const int* in_sizes, int n_in,
                              void* d_out, int out_size, void* d_ws, size_t ws_size,
                              hipStream_t stream)
{
    const float* h      = (const float*)d_in[0];
    const int*   src    = (const int*)  d_in[1];
    const int*   dst    = (const int*)  d_in[2];
    const float* sigma  = (const float*)d_in[3];
    const float* fc_w   = (const float*)d_in[4];
    const float* fc_b   = (const float*)d_in[5];
    const float* attn_w = (const float*)d_in[6];
    const float* attn_b = (const float*)d_in[7];
    const float* gamma  = (const float*)d_in[8];
    const float* beta   = (const float*)d_in[9];
    float* out = (float*)d_out;

    // workspace layout (~63 MB)
    float4* tmp    = (float4*)d_ws;                         // 800000 x 16B
    float4* ovf    = tmp + N_EDGES;                         // 1564*1024 x 16B spill
    __half* zh     = (__half*)(ovf + (size_t)NBK4 * OVFSTRIDE); // 50000*128 fp16
    float*  sv     = (float*)(zh + (size_t)N_NODES * 128);  // 50000
    float*  tv     = sv + N_NODES;                          // 50000
    float*  bns    = tv + N_NODES;                          // 256
    float*  parts  = bns + 256;                             // 512*256
    __half* wt     = (__half*)(parts + (size_t)NBLK_BN * 256); // 128*128 fp16 (W^T)
    int*    countsT= (int*)(wt + 16384);                    // 1564*784
    int*    cursC  = countsT + (size_t)NBK4 * NCH4;         // 784*1564
    int*    btot   = cursC + (size_t)NCH4 * NBK4;           // 1564
    int*    bbase  = btot + NBK4;                           // 1564

    k_prep    <<<NCHUNK, 256, 0, stream>>>(fc_w, wt, bns, dst, countsT);
    k_off     <<<NBK4 / 4, 256, 0, stream>>>(countsT, cursC, btot);
    k_gemm    <<<NBLK_GEMM, 256, 0, stream>>>(h, wt, fc_b, attn_w, zh, sv, tv);
    k_scat    <<<NCHUNK, 512, 0, stream>>>(src, dst, sigma, sv, tv, attn_b,
                                           cursC, btot, tmp, bbase);
    k_bagg    <<<NBUCKET, 512, 0, stream>>>(tmp, bbase, zh, ovf, out);
    k_bnstats <<<NBLK_BN, 256, 0, stream>>>(out, parts);
    k_bnred   <<<1, 1024, 0, stream>>>(parts, bns);
    k_bnapply <<<(N_NODES * 128) / (256 * 4), 256, 0, stream>>>(out, bns, gamma, beta);
}